// Round 11
// baseline (143.948 us; speedup 1.0000x reference)
//
#include <hip/hip_runtime.h>

// CRF loss on MI355X — register-to-register exchange via ds_bpermute (round 11).
// B=512, L=512, T=32, S=34. Output f32[512]. 512 blocks x 64 threads.
//
// R4/R8/R10 all land at ~71us with wildly different instruction mixes ->
// the serial ring is the LDS write->read round trip (2 per step). Fix:
// exchange states with ds_bpermute_b32 (lane pulls another lane's SRC
// OPERAND — no LDS memory, no write leg, no write->read ordering).
// Half-split carried from R10: lane (s,h)=(l&31,l>>5) accumulates input
// half p in [16h,16h+16) -> 16 bpermutes/chain/step with constant
// addresses (16h+p)*4; halves combine via v_permlane32_swap_b32 (VALU,
// verified R10). FMA pairing and summation order bit-identical to R10
// (absmax 0.0). No wave_barriers needed: bpermute is one instruction,
// all 64 lanes active throughout the loop (uniform control flow).
// Staggered slots as R8/R10: slot O = issue bwd exchange | fwd FMA,
// slot E = issue fwd exchange | bwd FMA. Emission ring, BIAS/rescale-16,
// gold-path epilogue unchanged (verified R3-R10).

#define F2   1.4426950408889634f   // log2(e)
#define LN2  0.6931471805599453f
#define BIAS 0.0078125f            // 2^-7, exact
#define BIASCNT 3577               // 7 * 511 applications of biased tc

__device__ __forceinline__ float grpmax32(float x) {
    // max over each 32-lane group: 4 DPP row_ror fmax + ds_swizzle xor-16.
    // (verified absmax 0.0 in rounds 4-6, 8-10)
    int t;
    t = __builtin_amdgcn_update_dpp(__float_as_int(x), __float_as_int(x), 0x121, 0xf, 0xf, true);
    x = fmaxf(x, __int_as_float(t));   // row_ror:1
    t = __builtin_amdgcn_update_dpp(__float_as_int(x), __float_as_int(x), 0x122, 0xf, 0xf, true);
    x = fmaxf(x, __int_as_float(t));   // row_ror:2
    t = __builtin_amdgcn_update_dpp(__float_as_int(x), __float_as_int(x), 0x124, 0xf, 0xf, true);
    x = fmaxf(x, __int_as_float(t));   // row_ror:4
    t = __builtin_amdgcn_update_dpp(__float_as_int(x), __float_as_int(x), 0x128, 0xf, 0xf, true);
    x = fmaxf(x, __int_as_float(t));   // row_ror:8 -> per-16 max
    t = __builtin_amdgcn_ds_swizzle(__float_as_int(x), 0x401F);  // xor 16
    x = fmaxf(x, __int_as_float(t));
    return x;
}

__device__ __forceinline__ float xhalf_sum(float v) {
    // sum of v over lane pairs (l, l^32) via v_permlane32_swap_b32 (VALU).
    // b is a distinct SSA def (opaque mov) so RA gives a,b distinct regs.
    // (verified absmax 0.0 in round 10)
    int a = __float_as_int(v);
    int b;
    asm("v_mov_b32 %0, %1" : "=v"(b) : "v"(a));
    asm("v_permlane32_swap_b32 %0, %1" : "+v"(a), "+v"(b));
    return __int_as_float(a) + __int_as_float(b);   // = v[l] + v[l^32]
}

__global__ __launch_bounds__(64, 1) void crf_kernel(
    const float* __restrict__ wtv,    // [512,512,32]
    const float* __restrict__ trans,  // [34,34]
    const int*   __restrict__ rtag,   // [512,512]
    float* __restrict__ out)          // [512]
{
    __shared__ __align__(16) float tlds[1156];  // raw translation (ln domain)
    __shared__ __align__(16) int   ltag[512];   // gold tags, 1 batch

    const int l = threadIdx.x;
    const int s = l & 31;        // state-1 (this lane's output state)
    const int h = l >> 5;        // input half: p in [16h, 16h+16)
    const int b = blockIdx.x;

    for (int k = l; k < 1156; k += 64) tlds[k] = trans[k];
    {
        const int* rtb = rtag + (size_t)b * 512;
        for (int k = l; k < 512; k += 64) ltag[k] = rtb[k];
    }
    __syncthreads();  // once, before the main loop (graph-safe)

    // exp2-domain transitions (biased), scalar, same values/pairing as R10:
    // slot k covers inputs p0 = 16h+4k .. p0+3.
    float tcF[16], tcB[16];
    #pragma unroll
    for (int k = 0; k < 4; ++k) {
        const int p0 = 16 * h + 4 * k;
        #pragma unroll
        for (int j = 0; j < 4; ++j) {
            tcF[4 * k + j] = __builtin_exp2f(F2 * tlds[(p0 + j + 1) * 34 + (s + 1)]) * BIAS;
            tcB[4 * k + j] = __builtin_exp2f(F2 * tlds[(s + 1) * 34 + (p0 + j + 1)]) * BIAS;
        }
    }
    // START term (fwd, step 1): added in half 0's partial only
    float ai = (h == 0) ? __builtin_exp2f(F2 * tlds[s + 1]) * BIAS : 0.0f;

    const float* wbq = wtv + (size_t)b * (512 * 32);
    const float* wl  = wbq + s;

    float stF = __builtin_exp2f(F2 * wl[0]);    // alpha_0 (replicated both halves)
    float stB = 1.0f;                           // b_511
    int scF = 0, scB = 0;

    // emission ring (8 ahead): step i uses row i (fwd) / 512-i (bwd)
    float vnF[16], vnB[16];
    #pragma unroll
    for (int j = 0; j < 8; ++j) {
        vnF[j] = wl[(1 + j) * 32];             // rows 1..8
        vnB[j] = wl[(511 - j) * 32];           // rows 511..504
    }
    float eoF_c = __builtin_exp2f(F2 * vnF[0]);   // emission factor, step 1
    float gB    = __builtin_exp2f(F2 * vnB[0]);   // g_1 = b_511 * eo(row 511)

    // bpermute addresses (bytes): lane pulls state 16h+p from lane 16h+p
    int addr[16];
    #pragma unroll
    for (int p = 0; p < 16; ++p) addr[p] = (16 * h + p) * 4;

    int vF[16], vB[16];

    // ---- prologue: exchange alpha_0 (fwd) ----
    #pragma unroll
    for (int p = 0; p < 16; ++p)
        vF[p] = __builtin_amdgcn_ds_bpermute(addr[p], __float_as_int(stF));

    for (int t0 = 1; t0 <= 241; t0 += 16) {   // 16 bodies x 16 steps = i = 1..256
        #pragma unroll
        for (int j = 0; j < 16; ++j) {
            const int i = t0 + j;

            // ---- SLOT O: issue bwd exchange (src = g_i) | shadow |
            //      fwd half-FMA + cross-half combine, step i ----
            #pragma unroll
            for (int p = 0; p < 16; ++p)
                vB[p] = __builtin_amdgcn_ds_bpermute(addr[p], __float_as_int(gB));
            // shadow: bwd emission prefetch (tail rows >= 248: in-bounds) +
            // next-step bwd emission factor
            vnB[(j + 8) & 15] = wl[(512 - (i + 8)) * 32];
            float eoB_n = __builtin_exp2f(F2 * vnB[(j + 1) & 15]);
            {
                float A = ai, Bc = 0.0f, C = 0.0f, D = 0.0f;
                ai = 0.0f;
                #pragma unroll
                for (int k = 0; k < 4; ++k) {
                    A  = fmaf(__int_as_float(vF[4 * k + 0]), tcF[4 * k + 0], A);
                    Bc = fmaf(__int_as_float(vF[4 * k + 1]), tcF[4 * k + 1], Bc);
                    C  = fmaf(__int_as_float(vF[4 * k + 2]), tcF[4 * k + 2], C);
                    D  = fmaf(__int_as_float(vF[4 * k + 3]), tcF[4 * k + 3], D);
                }
                float part = (A + Bc) + (C + D);
                float sum  = xhalf_sum(part);            // full 32-input dot
                stF = sum * eoF_c;                       // fwd updates all i
            }
            if (j == 15) {
                // fwd rescale (every 16 steps) between update and next exchange
                float m = grpmax32(stF);
                int e = ((__float_as_int(m) >> 23) & 0xff) - 127;
                stF *= __int_as_float((127 - e) << 23);
                scF += e;
            }

            // ---- SLOT E: issue fwd exchange (src = alpha_i) | shadow |
            //      bwd half-FMA + combine, step i ----
            #pragma unroll
            for (int p = 0; p < 16; ++p)
                vF[p] = __builtin_amdgcn_ds_bpermute(addr[p], __float_as_int(stF));
            // shadow: fwd emission prefetch (tail rows <= 264: in-bounds) +
            // next-step fwd emission factor
            vnF[(j + 8) & 15] = wl[(i + 8) * 32];
            float eoF_n = __builtin_exp2f(F2 * vnF[(j + 1) & 15]);
            {
                float A = 0.0f, Bc = 0.0f, C = 0.0f, D = 0.0f;
                #pragma unroll
                for (int k = 0; k < 4; ++k) {
                    A  = fmaf(__int_as_float(vB[4 * k + 0]), tcB[4 * k + 0], A);
                    Bc = fmaf(__int_as_float(vB[4 * k + 1]), tcB[4 * k + 1], Bc);
                    C  = fmaf(__int_as_float(vB[4 * k + 2]), tcB[4 * k + 2], C);
                    D  = fmaf(__int_as_float(vB[4 * k + 3]), tcB[4 * k + 3], D);
                }
                float part = (A + Bc) + (C + D);
                float sum  = xhalf_sum(part);
                stB = (i != 256) ? sum : stB;            // i==256: fwd-only tail
            }
            if (j == 15) {
                // bwd rescale at body end (before next exchange)
                float m = grpmax32(stB);
                int e = ((__float_as_int(m) >> 23) & 0xff) - 127;
                stB *= __int_as_float((127 - e) << 23);
                scB += e;
            }
            gB    = stB * eoB_n;   // exchange value for step i+1 (off issue path)
            eoF_c = eoF_n;
        }
    }

    // ---- Z = sum_s af_256[s] * b_256[s] (halves hold identical replicas) ----
    float prod = stF * stB;
    prod += __shfl_xor(prod, 1);
    prod += __shfl_xor(prod, 2);
    prod += __shfl_xor(prod, 4);
    prod += __shfl_xor(prod, 8);
    prod += __shfl_xor(prod, 16);
    float total = ((float)(scF + scB + BIASCNT) + __builtin_log2f(prod)) * LN2;

    // ---- gold-path score epilogue (verified R3-R10), 1 batch ----
    const int* tg = ltag;
    int   tcur[8];
    float em[8];
    #pragma unroll
    for (int k = 0; k < 8; ++k) tcur[k] = tg[l + 64 * k];
    #pragma unroll
    for (int k = 0; k < 8; ++k) em[k] = wbq[(l + 64 * k) * 32 + (tcur[k] - 1)];
    float acc = 0.0f;
    #pragma unroll
    for (int k = 0; k < 8; ++k) {
        int t  = l + 64 * k;
        int nx = tg[(t + 1) & 511];
        nx = (t == 511) ? 33 : nx;            // end term trans[tag_511][STOP]
        acc += em[k] + tlds[tcur[k] * 34 + nx];
    }
    if (l == 0) acc += tlds[tg[0]];           // start term trans[0][tag_0]
    acc += __shfl_xor(acc, 1);
    acc += __shfl_xor(acc, 2);
    acc += __shfl_xor(acc, 4);
    acc += __shfl_xor(acc, 8);
    acc += __shfl_xor(acc, 16);
    acc += __shfl_xor(acc, 32);

    if (l == 0) out[b] = total - acc;
}

extern "C" void kernel_launch(void* const* d_in, const int* in_sizes, int n_in,
                              void* d_out, int out_size, void* d_ws, size_t ws_size,
                              hipStream_t stream) {
    const float* wtv   = (const float*)d_in[0];
    const float* trans = (const float*)d_in[1];
    const int*   rtag  = (const int*)d_in[2];
    (void)in_sizes; (void)n_in; (void)d_ws; (void)ws_size; (void)out_size;
    float* out = (float*)d_out;
    crf_kernel<<<512, 64, 0, stream>>>(wtv, trans, rtag, out);
}